// Round 15
// baseline (110.777 us; speedup 1.0000x reference)
//
#include <hip/hip_runtime.h>
#include <hip/hip_bf16.h>

typedef unsigned short u16;
typedef unsigned int u32;
typedef __attribute__((ext_vector_type(8))) short short8;
typedef __attribute__((ext_vector_type(4))) float f32x4;

#define H 8
#define N 384
#define D 32
#define CIN 256
#define HNN (H * N * N)
#define SCALER 0.17677669529663687f
#define EPS 1e-9f

// workspace float offsets
#define PROJ_OFF 0u              // 5*H*N*D = 491520: a,b,c,vj,vk as [5][H][N][D]
#define S_OFF    491520u         // 3*H*N*N: t=0 XT[k][j], t=1 YT[i][k], t=2 Z[i][j]
#define VJT_OFF  4030464u        // H*D*N = 98304: vj transposed [h][d][n]
#define VKT_OFF  4128768u        // H*D*N
#define MX_OFF   4227072u        // 8 floats (decoded global max of X per head)
#define NUM_OFF  4233224u        // H*N*D
#define DEN_OFF  4331528u        // H*N
#define XBF_OFF  4334600u        // ushort[H*N*N]: X packed in MFMA-frag order
#define ZBF_OFF  4924424u        // ushort[H*N*N] (Z bf16, row-major)
#define KEYS_OFF 5514248u        // u32 keys: mXrowK[H*N], mYK[H*N], mZK[H*N] (memset 0 per call)

__device__ inline float bf2f(u16 u) {
    union { unsigned int x; float f; } c; c.x = ((unsigned int)u) << 16; return c.f;
}
__device__ inline u16 f2bf(float f) {
    unsigned int x = __float_as_uint(f);
    return (u16)((x + 0x7FFFu + ((x >> 16) & 1u)) >> 16);
}
// order-preserving float->uint key (exact; atomicMax-able); 0 is below all keys
__device__ inline u32 fkey(float f) {
    u32 u = __float_as_uint(f);
    return (u >> 31) ? ~u : (u | 0x80000000u);
}
__device__ inline float fkey_dec(u32 k) {
    return (k >> 31) ? __uint_as_float(k ^ 0x80000000u) : __uint_as_float(~k);
}

// ---------------- K1: projection GEMM  wx[n,m] = sum_k hs[n,k]*W[m,k] ----------------
__global__ __launch_bounds__(256) void proj_kernel(const float* __restrict__ hs,
                                                   const float* __restrict__ W,
                                                   float* __restrict__ proj,
                                                   float* __restrict__ projT) {
    __shared__ float hs_s[64][68];
    __shared__ float w_s[64][68];
    const int tid = threadIdx.x;
    const int tx = tid & 15, ty = tid >> 4;
    const int m0 = blockIdx.x * 64, n0 = blockIdx.y * 64;
    float acc[4][4] = {};
    for (int k0 = 0; k0 < CIN; k0 += 64) {
        __syncthreads();
#pragma unroll
        for (int rep = 0; rep < 4; ++rep) {
            int lin = rep * 1024 + tid * 4;
            int rl = lin >> 6, kl = lin & 63;
            float4 hv = *(const float4*)&hs[(n0 + rl) * CIN + k0 + kl];
            hs_s[kl + 0][rl] = hv.x; hs_s[kl + 1][rl] = hv.y;
            hs_s[kl + 2][rl] = hv.z; hs_s[kl + 3][rl] = hv.w;
            float4 wv = *(const float4*)&W[(m0 + rl) * CIN + k0 + kl];
            w_s[kl + 0][rl] = wv.x; w_s[kl + 1][rl] = wv.y;
            w_s[kl + 2][rl] = wv.z; w_s[kl + 3][rl] = wv.w;
        }
        __syncthreads();
#pragma unroll 16
        for (int kk = 0; kk < 64; ++kk) {
            float4 a4 = *(const float4*)&hs_s[kk][ty * 4];
            float4 b4 = *(const float4*)&w_s[kk][tx * 4];
            float av[4] = {a4.x, a4.y, a4.z, a4.w};
            float bv[4] = {b4.x, b4.y, b4.z, b4.w};
#pragma unroll
            for (int a_ = 0; a_ < 4; ++a_) {
#pragma unroll
                for (int b_ = 0; b_ < 4; ++b_) {
                    acc[a_][b_] = fmaf(av[a_], bv[b_], acc[a_][b_]);
                }
            }
        }
    }
#pragma unroll
    for (int a_ = 0; a_ < 4; ++a_) {
        int n = n0 + ty * 4 + a_;
#pragma unroll
        for (int b_ = 0; b_ < 4; ++b_) {
            int m = m0 + tx * 4 + b_;
            int s = m >> 8, hh = (m >> 5) & 7, d = m & 31;
            proj[s * (H * N * D) + hh * (N * D) + n * D + d] = acc[a_][b_];
            if (s >= 3) projT[(s - 3) * (H * D * N) + hh * (D * N) + d * N + n] = acc[a_][b_];
        }
    }
}

// ---------------- K2: scores + fused row-max atomics ----------------
__global__ __launch_bounds__(256) void scores_kernel(const float* __restrict__ proj,
                                                     float* __restrict__ S,
                                                     u32* __restrict__ keys) {
    __shared__ float LsT[32][68];
    __shared__ float RsT[32][68];
    const int tid = threadIdx.x, tx = tid & 15, ty = tid >> 4;
    const int rt = blockIdx.x % 6, ct = blockIdx.x / 6;
    const int r0 = rt * 64, c0 = ct * 64;
    const int h = blockIdx.y;
    const int t = blockIdx.z;
    const int Lidx = (t == 0) ? 2 : 0;
    const int Ridx = (t == 1) ? 2 : 1;
    const float* Lp = proj + Lidx * (H * N * D) + h * (N * D);
    const float* Rp = proj + Ridx * (H * N * D) + h * (N * D);
    float* Sp = S + t * HNN + h * (N * N);
    u32* krow = keys + t * (H * N) + h * N;
    {
        int i = tid >> 2, d8 = (tid & 3) * 8;
        float4 v0 = *(const float4*)&Lp[(r0 + i) * D + d8];
        float4 v1 = *(const float4*)&Lp[(r0 + i) * D + d8 + 4];
        LsT[d8 + 0][i] = v0.x; LsT[d8 + 1][i] = v0.y; LsT[d8 + 2][i] = v0.z; LsT[d8 + 3][i] = v0.w;
        LsT[d8 + 4][i] = v1.x; LsT[d8 + 5][i] = v1.y; LsT[d8 + 6][i] = v1.z; LsT[d8 + 7][i] = v1.w;
        float4 w0 = *(const float4*)&Rp[(c0 + i) * D + d8];
        float4 w1 = *(const float4*)&Rp[(c0 + i) * D + d8 + 4];
        RsT[d8 + 0][i] = w0.x; RsT[d8 + 1][i] = w0.y; RsT[d8 + 2][i] = w0.z; RsT[d8 + 3][i] = w0.w;
        RsT[d8 + 4][i] = w1.x; RsT[d8 + 5][i] = w1.y; RsT[d8 + 6][i] = w1.z; RsT[d8 + 7][i] = w1.w;
    }
    __syncthreads();
    float acc[4][4] = {};
#pragma unroll
    for (int dd = 0; dd < 32; ++dd) {
        float4 l4 = *(const float4*)&LsT[dd][ty * 4];
        float4 r4 = *(const float4*)&RsT[dd][tx * 4];
        float lv[4] = {l4.x, l4.y, l4.z, l4.w};
        float rv[4] = {r4.x, r4.y, r4.z, r4.w};
#pragma unroll
        for (int a_ = 0; a_ < 4; ++a_) {
#pragma unroll
            for (int b_ = 0; b_ < 4; ++b_) {
                acc[a_][b_] = fmaf(lv[a_], rv[b_], acc[a_][b_]);
            }
        }
    }
#pragma unroll
    for (int a_ = 0; a_ < 4; ++a_) {
        float4 o;
        o.x = acc[a_][0] * SCALER; o.y = acc[a_][1] * SCALER;
        o.z = acc[a_][2] * SCALER; o.w = acc[a_][3] * SCALER;
        *(float4*)&Sp[(r0 + ty * 4 + a_) * N + c0 + tx * 4] = o;
        float rm = fmaxf(fmaxf(o.x, o.y), fmaxf(o.z, o.w));
        rm = fmaxf(rm, __shfl_xor(rm, 1));
        rm = fmaxf(rm, __shfl_xor(rm, 2));
        rm = fmaxf(rm, __shfl_xor(rm, 4));
        rm = fmaxf(rm, __shfl_xor(rm, 8));
        if (tx == 0) atomicMax(&krow[r0 + ty * 4 + a_], fkey(rm));
    }
}

// ---------------- K3: reduce mXrow keys -> mX[h] float; grid 8 x 64 ----------------
__global__ void reduce_mx_kernel(const u32* __restrict__ keys, float* __restrict__ mX) {
    const int h = blockIdx.x;
    const int lane = threadIdx.x;
    u32 m = 0;
    for (int q = lane; q < N; q += 64) m = max(m, keys[h * N + q]);
#pragma unroll
    for (int off = 32; off; off >>= 1) m = max(m, (u32)__shfl_down(m, off));
    if (lane == 0) mX[h] = fkey_dec(m);
}

// ---------------- K4: exp ----------------
// Xpack layout: [h][kt=k/16][jt=j/32][lane][8], lane = (k&15) | ((j>>3)&3)<<4  (B-frag order)
__global__ void exp_kernel(float* __restrict__ S, const float* __restrict__ mX,
                           const u32* __restrict__ keys,
                           u16* __restrict__ Xbf, u16* __restrict__ Zbf) {
    int f8 = blockIdx.x * 256 + threadIdx.x;  // 442368 total
    int flat = f8 * 8;
    int t = flat / HNN;
    int rem = flat - t * HNN;
    int h = rem / (N * N);
    int rc = rem - h * (N * N);
    int r = rc / N;
    int c = rc - r * N;
    float m = (t == 0) ? mX[h] : fkey_dec(keys[t * (H * N) + h * N + r]);
    float4 v0 = *(float4*)&S[flat];
    float4 v1 = *(float4*)&S[flat + 4];
    float e[8] = {__expf(v0.x - m), __expf(v0.y - m), __expf(v0.z - m), __expf(v0.w - m),
                  __expf(v1.x - m), __expf(v1.y - m), __expf(v1.z - m), __expf(v1.w - m)};
    if (t == 1) {
        float4 o0 = {e[0], e[1], e[2], e[3]}, o1 = {e[4], e[5], e[6], e[7]};
        *(float4*)&S[flat] = o0;
        *(float4*)&S[flat + 4] = o1;
    } else {
        short8 ov;
#pragma unroll
        for (int q = 0; q < 8; ++q) ov[q] = (short)f2bf(e[q]);
        if (t == 0) {
            const int kt = r >> 4, jt = c >> 5;
            const int lanep = (r & 15) | (((c >> 3) & 3) << 4);
            u16* dst = Xbf + (((h * 24 + kt) * 12 + jt) << 9) + lanep * 8;
            *(short8*)dst = ov;
        } else {
            u16* dst = Zbf + h * (N * N) + rc;
            *(short8*)dst = ov;
        }
    }
}

// ---------------- K5: cubic contraction via MFMA bf16, v13 (A+B register ping-pong) ----------------
// block = (h, i-tile of 64, d-group of 2). 768 thr = 12 waves, wave owns 32 k (2 k-tiles).
// A LDS frag-packed (zero read conflicts); B global frag-packed (1KB bursts).
// NEW: A-frags ping-pong prefetched one js ahead (like B) -> MFMA never waits on fresh
// LDS reads; the lgkm wait before each MFMA block covers loads issued one phase earlier.
// Regs: acc 64 + A 2x32 + B 16 + addr ~ 160 <= 170 cap (768,3). Tripwire: WRITE_SIZE.
__global__ __launch_bounds__(768, 3) void cubic_mfma(
        const u16* __restrict__ Xbf, const u16* __restrict__ Zbf,
        const float* __restrict__ Yt, const float* __restrict__ vjT,
        const float* __restrict__ vkT, float* __restrict__ NumB,
        float* __restrict__ DenB) {
    const int orig = blockIdx.x;             // 0..815 (816 = 8 x 102, bijective)
    const int wg = (orig & 7) * 102 + (orig >> 3);
    const int h   = wg / 102;                // one head per XCD
    const int rem = wg - h * 102;
    const int dg  = rem / 6;                 // 0..16
    const int it6 = rem - dg * 6;            // 0..5
    const int i0  = it6 * 64;
    const bool dgden = (dg == 16);
    const int d0 = dgden ? 0 : 2 * dg;
    const int d1 = dgden ? 0 : 2 * dg + 1;
    const int tid = threadIdx.x;
    const int w = tid >> 6, lane = tid & 63;
    __shared__ u16 A_lds[2 * 64 * N];        // [t][f(48)][64][8] frag-packed
    __shared__ float red[2][12][64];
    u16* A0 = A_lds;
    u16* A1 = A_lds + 64 * N;
    const u16* Zh = Zbf + h * (N * N);
    const float* Yth = Yt + h * (N * N);
    const float* vjd0 = vjT + h * (D * N) + d0 * N;
    const float* vjd1 = vjT + h * (D * N) + d1 * N;
    const float* vkd0 = vkT + h * (D * N) + d0 * N;
    const float* vkd1 = vkT + h * (D * N) + d1 * N;

    // ---- A-prep: coalesced global reads, frag-packed LDS writes (both tiles)
    {
#pragma unroll
        for (int it = 0; it < 4; ++it) {
            const int g = it * 768 + tid;        // 0..3071
            const int row = g / 48;
            const int cb = g - row * 48;
            const int jb = cb * 8;
            const int fi = row >> 4, l15r = row & 15;
            const int js = cb >> 2, sub = cb & 3;
            const int f = fi * 12 + js;
            const int dst = f * 512 + (((l15r | (sub << 4)) ^ (f & 7)) << 3);
            short8 zv = *(const short8*)&Zh[(i0 + row) * N + jb];
            if (dgden) {
                *(short8*)&A0[dst] = zv;
                *(short8*)&A1[dst] = zv;
            } else {
                float4 p0 = *(const float4*)&vjd0[jb];
                float4 p1 = *(const float4*)&vjd0[jb + 4];
                float4 q0 = *(const float4*)&vjd1[jb];
                float4 q1 = *(const float4*)&vjd1[jb + 4];
                float v0[8] = {p0.x, p0.y, p0.z, p0.w, p1.x, p1.y, p1.z, p1.w};
                float v1[8] = {q0.x, q0.y, q0.z, q0.w, q1.x, q1.y, q1.z, q1.w};
                short8 o0, o1;
#pragma unroll
                for (int e = 0; e < 8; ++e) {
                    float zf = bf2f((u16)zv[e]);
                    o0[e] = (short)f2bf(zf * v0[e]);
                    o1[e] = (short)f2bf(zf * v1[e]);
                }
                *(short8*)&A0[dst] = o0;
                *(short8*)&A1[dst] = o1;
            }
        }
    }
    __syncthreads();

    // ---- MFMA main loop: no barriers; A and B both ping-pong prefetched
    f32x4 acc0[4][2], acc1[4][2];
#pragma unroll
    for (int fi = 0; fi < 4; ++fi)
#pragma unroll
        for (int fk = 0; fk < 2; ++fk) {
            acc0[fi][fk] = (f32x4){0.f, 0.f, 0.f, 0.f};
            acc1[fi][fk] = (f32x4){0.f, 0.f, 0.f, 0.f};
        }

    const int l15 = lane & 15;
    const int kwb = w * 32 + l15;
    const u16* Bp = Xbf + ((h * 24 + w * 2) * 12 << 9) + lane * 8;
    const int FST = 512;              // u16 per frag
    const int KT1 = 12 * 512;         // second k-tile offset

    short8 pa0[4], pa1[4], qa0[4], qa1[4];
    short8 pb[2], qb[2];
#pragma unroll
    for (int fi = 0; fi < 4; ++fi) {
        const int f = fi * 12;
        const int off = f * 512 + ((lane ^ (f & 7)) << 3);
        pa0[fi] = *(const short8*)&A0[off];
        pa1[fi] = *(const short8*)&A1[off];
    }
    pb[0] = *(const short8*)&Bp[0];
    pb[1] = *(const short8*)&Bp[KT1];

#pragma unroll
    for (int it = 0; it < 6; ++it) {
        const int js1 = 2 * it + 1;
        {   // prefetch js1 into q (A + B)
#pragma unroll
            for (int fi = 0; fi < 4; ++fi) {
                const int f = fi * 12 + js1;
                const int off = f * 512 + ((lane ^ (f & 7)) << 3);
                qa0[fi] = *(const short8*)&A0[off];
                qa1[fi] = *(const short8*)&A1[off];
            }
            qb[0] = *(const short8*)&Bp[js1 * FST];
            qb[1] = *(const short8*)&Bp[KT1 + js1 * FST];
        }
        {   // compute js0 with p
#pragma unroll
            for (int fk = 0; fk < 2; ++fk) {
#pragma unroll
                for (int fi = 0; fi < 4; ++fi) {
                    acc0[fi][fk] = __builtin_amdgcn_mfma_f32_16x16x32_bf16(pa0[fi], pb[fk], acc0[fi][fk], 0, 0, 0);
                    acc1[fi][fk] = __builtin_amdgcn_mfma_f32_16x16x32_bf16(pa1[fi], pb[fk], acc1[fi][fk], 0, 0, 0);
                }
            }
        }
        if (it < 5) {   // prefetch js0+2 into p
#pragma unroll
            for (int fi = 0; fi < 4; ++fi) {
                const int f = fi * 12 + js1 + 1;
                const int off = f * 512 + ((lane ^ (f & 7)) << 3);
                pa0[fi] = *(const short8*)&A0[off];
                pa1[fi] = *(const short8*)&A1[off];
            }
            pb[0] = *(const short8*)&Bp[(js1 + 1) * FST];
            pb[1] = *(const short8*)&Bp[KT1 + (js1 + 1) * FST];
        }
        {   // compute js1 with q
#pragma unroll
            for (int fk = 0; fk < 2; ++fk) {
#pragma unroll
                for (int fi = 0; fi < 4; ++fi) {
                    acc0[fi][fk] = __builtin_amdgcn_mfma_f32_16x16x32_bf16(qa0[fi], qb[fk], acc0[fi][fk], 0, 0, 0);
                    acc1[fi][fk] = __builtin_amdgcn_mfma_f32_16x16x32_bf16(qa1[fi], qb[fk], acc1[fi][fk], 0, 0, 0);
                }
            }
        }
    }

    // ---- epilogue: weight by YT[i,k]*vk[k,d], reduce over k; d0 then d1 (caps reg peak)
    const int rbase = (lane >> 4) << 2;
    {   // d0
        float np[4][4];
#pragma unroll
        for (int fi = 0; fi < 4; ++fi)
#pragma unroll
            for (int reg = 0; reg < 4; ++reg) np[fi][reg] = 0.f;
#pragma unroll
        for (int fk = 0; fk < 2; ++fk) {
            const int kcol = kwb + fk * 16;
            const float vkv = dgden ? 1.0f : vkd0[kcol];
#pragma unroll
            for (int fi = 0; fi < 4; ++fi) {
#pragma unroll
                for (int reg = 0; reg < 4; ++reg) {
                    const int irow = i0 + fi * 16 + rbase + reg;
                    const float wgt = Yth[irow * N + kcol] * vkv;
                    np[fi][reg] = fmaf(acc0[fi][fk][reg], wgt, np[fi][reg]);
                }
            }
        }
#pragma unroll
        for (int fi = 0; fi < 4; ++fi) {
#pragma unroll
            for (int reg = 0; reg < 4; ++reg) {
                float v = np[fi][reg];
                v += __shfl_xor(v, 1); v += __shfl_xor(v, 2);
                v += __shfl_xor(v, 4); v += __shfl_xor(v, 8);
                np[fi][reg] = v;
            }
        }
        if (l15 == 0) {
#pragma unroll
            for (int fi = 0; fi < 4; ++fi)
#pragma unroll
                for (int reg = 0; reg < 4; ++reg)
                    red[0][w][fi * 16 + rbase + reg] = np[fi][reg];
        }
    }
    {   // d1
        float np[4][4];
#pragma unroll
        for (int fi = 0; fi < 4; ++fi)
#pragma unroll
            for (int reg = 0; reg < 4; ++reg) np[fi][reg] = 0.f;
#pragma unroll
        for (int fk = 0; fk < 2; ++fk) {
            const int kcol = kwb + fk * 16;
            const float vkv = dgden ? 1.0f : vkd1[kcol];
#pragma unroll
            for (int fi = 0; fi < 4; ++fi) {
#pragma unroll
                for (int reg = 0; reg < 4; ++reg) {
                    const int irow = i0 + fi * 16 + rbase + reg;
                    const float wgt = Yth[irow * N + kcol] * vkv;
                    np[fi][reg] = fmaf(acc1[fi][fk][reg], wgt, np[fi][reg]);
                }
            }
        }
#pragma unroll
        for (int fi = 0; fi < 4; ++fi) {
#pragma unroll
            for (int reg = 0; reg < 4; ++reg) {
                float v = np[fi][reg];
                v += __shfl_xor(v, 1); v += __shfl_xor(v, 2);
                v += __shfl_xor(v, 4); v += __shfl_xor(v, 8);
                np[fi][reg] = v;
            }
        }
        if (l15 == 0) {
#pragma unroll
            for (int fi = 0; fi < 4; ++fi)
#pragma unroll
                for (int reg = 0; reg < 4; ++reg)
                    red[1][w][fi * 16 + rbase + reg] = np[fi][reg];
        }
    }
    __syncthreads();
    if (tid < 64) {
        float s = 0.f;
#pragma unroll
        for (int ww = 0; ww < 12; ++ww) s += red[0][ww][tid];
        if (!dgden) NumB[h * (N * D) + (i0 + tid) * D + 2 * dg] = s;
        else        DenB[h * N + i0 + tid] = s;
    } else if (tid < 128 && !dgden) {
        const int i = tid - 64;
        float s = 0.f;
#pragma unroll
        for (int ww = 0; ww < 12; ++ww) s += red[1][ww][i];
        NumB[h * (N * D) + (i0 + i) * D + 2 * dg + 1] = s;
    }
}

// ---------------- K6: normalize + fp32 output [n, h*D+d] ----------------
__global__ void out_kernel(const float* __restrict__ NumB, const float* __restrict__ DenB,
                           float* __restrict__ out) {
    int idx = blockIdx.x * 256 + threadIdx.x;  // 0..98303
    int n = idx >> 8;
    int ch = idx & 255;
    int hh = ch >> 5, d = ch & 31;
    float v = NumB[hh * (N * D) + n * D + d] / (DenB[hh * N + n] + EPS);
    out[idx] = v;
}

extern "C" void kernel_launch(void* const* d_in, const int* in_sizes, int n_in,
                              void* d_out, int out_size, void* d_ws, size_t ws_size,
                              hipStream_t stream) {
    const float* hs = (const float*)d_in[0];
    const float* W  = (const float*)d_in[1];
    float* ws = (float*)d_ws;
    float* proj  = ws + PROJ_OFF;
    float* S     = ws + S_OFF;
    float* projT = ws + VJT_OFF;    // vj rows, then vk rows at +H*D*N
    float* mX    = ws + MX_OFF;
    float* NumB  = ws + NUM_OFF;
    float* DenB  = ws + DEN_OFF;
    u16*   Xbf   = (u16*)(ws + XBF_OFF);
    u16*   Zbf   = (u16*)(ws + ZBF_OFF);
    u32*   keys  = (u32*)(ws + KEYS_OFF);   // 3*H*N keys
    float* out = (float*)d_out;

    hipMemsetAsync(keys, 0, 3 * H * N * sizeof(u32), stream);
    proj_kernel<<<dim3(20, 6), 256, 0, stream>>>(hs, W, proj, projT);
    scores_kernel<<<dim3(36, 8, 3), 256, 0, stream>>>(proj, S, keys);
    reduce_mx_kernel<<<8, 64, 0, stream>>>(keys, mX);
    exp_kernel<<<1728, 256, 0, stream>>>(S, mX, keys, Xbf, Zbf);
    cubic_mfma<<<dim3(816), 768, 0, stream>>>(Xbf, Zbf, S + HNN, ws + VJT_OFF,
                                              ws + VKT_OFF, NumB, DenB);
    out_kernel<<<(H * N * D) / 256, 256, 0, stream>>>(NumB, DenB, out);
}

// Round 16
// 100.730 us; speedup vs baseline: 1.0997x; 1.0997x over previous
//
#include <hip/hip_runtime.h>
#include <hip/hip_bf16.h>

typedef unsigned short u16;
typedef unsigned int u32;
typedef __attribute__((ext_vector_type(8))) short short8;
typedef __attribute__((ext_vector_type(4))) float f32x4;

#define H 8
#define N 384
#define D 32
#define CIN 256
#define HNN (H * N * N)
#define SCALER 0.17677669529663687f
#define EPS 1e-9f

// workspace float offsets
#define PROJ_OFF 0u              // 5*H*N*D = 491520: a,b,c,vj,vk as [5][H][N][D]
#define S_OFF    491520u         // 3*H*N*N: t=0 XT[k][j], t=1 YT[i][k], t=2 Z[i][j]
#define VJT_OFF  4030464u        // H*D*N = 98304: vj transposed [h][d][n]
#define VKT_OFF  4128768u        // H*D*N
#define MX_OFF   4227072u        // 8 floats (decoded global max of X per head)
#define NUM_OFF  4233224u        // H*N*D
#define DEN_OFF  4331528u        // H*N
#define XBF_OFF  4334600u        // ushort[H*N*N]: X packed in MFMA-frag order
#define ZBF_OFF  4924424u        // ushort[H*N*N] (Z bf16, row-major)
#define KEYS_OFF 5514248u        // u32 keys: mXrowK[H*N], mYK[H*N], mZK[H*N] (memset 0 per call)
#define LBF_OFF  5523464u        // u16[3*H*N*D]: bf16 copies of a,b,c for scores MFMA

__device__ inline float bf2f(u16 u) {
    union { unsigned int x; float f; } c; c.x = ((unsigned int)u) << 16; return c.f;
}
__device__ inline u16 f2bf(float f) {
    unsigned int x = __float_as_uint(f);
    return (u16)((x + 0x7FFFu + ((x >> 16) & 1u)) >> 16);
}
// order-preserving float->uint key (exact; atomicMax-able); 0 is below all keys
__device__ inline u32 fkey(float f) {
    u32 u = __float_as_uint(f);
    return (u >> 31) ? ~u : (u | 0x80000000u);
}
__device__ inline float fkey_dec(u32 k) {
    return (k >> 31) ? __uint_as_float(k ^ 0x80000000u) : __uint_as_float(~k);
}

// ---------------- K1: projection GEMM  wx[n,m] = sum_k hs[n,k]*W[m,k] ----------------
// also emits bf16 copies of a,b,c (s<3) for the MFMA scores kernel
__global__ __launch_bounds__(256) void proj_kernel(const float* __restrict__ hs,
                                                   const float* __restrict__ W,
                                                   float* __restrict__ proj,
                                                   float* __restrict__ projT,
                                                   u16* __restrict__ Lbf) {
    __shared__ float hs_s[64][68];
    __shared__ float w_s[64][68];
    const int tid = threadIdx.x;
    const int tx = tid & 15, ty = tid >> 4;
    const int m0 = blockIdx.x * 64, n0 = blockIdx.y * 64;
    float acc[4][4] = {};
    for (int k0 = 0; k0 < CIN; k0 += 64) {
        __syncthreads();
#pragma unroll
        for (int rep = 0; rep < 4; ++rep) {
            int lin = rep * 1024 + tid * 4;
            int rl = lin >> 6, kl = lin & 63;
            float4 hv = *(const float4*)&hs[(n0 + rl) * CIN + k0 + kl];
            hs_s[kl + 0][rl] = hv.x; hs_s[kl + 1][rl] = hv.y;
            hs_s[kl + 2][rl] = hv.z; hs_s[kl + 3][rl] = hv.w;
            float4 wv = *(const float4*)&W[(m0 + rl) * CIN + k0 + kl];
            w_s[kl + 0][rl] = wv.x; w_s[kl + 1][rl] = wv.y;
            w_s[kl + 2][rl] = wv.z; w_s[kl + 3][rl] = wv.w;
        }
        __syncthreads();
#pragma unroll 16
        for (int kk = 0; kk < 64; ++kk) {
            float4 a4 = *(const float4*)&hs_s[kk][ty * 4];
            float4 b4 = *(const float4*)&w_s[kk][tx * 4];
            float av[4] = {a4.x, a4.y, a4.z, a4.w};
            float bv[4] = {b4.x, b4.y, b4.z, b4.w};
#pragma unroll
            for (int a_ = 0; a_ < 4; ++a_) {
#pragma unroll
                for (int b_ = 0; b_ < 4; ++b_) {
                    acc[a_][b_] = fmaf(av[a_], bv[b_], acc[a_][b_]);
                }
            }
        }
    }
#pragma unroll
    for (int a_ = 0; a_ < 4; ++a_) {
        int n = n0 + ty * 4 + a_;
#pragma unroll
        for (int b_ = 0; b_ < 4; ++b_) {
            int m = m0 + tx * 4 + b_;
            int s = m >> 8, hh = (m >> 5) & 7, d = m & 31;
            proj[s * (H * N * D) + hh * (N * D) + n * D + d] = acc[a_][b_];
            if (s >= 3) projT[(s - 3) * (H * D * N) + hh * (D * N) + d * N + n] = acc[a_][b_];
            else        Lbf[((s * H + hh) * N + n) * D + d] = f2bf(acc[a_][b_]);
        }
    }
}

// ---------------- K2: scores via MFMA bf16 + fused row-max atomics ----------------
// t=0: XT[k,j] = c.b ; t=1: YT[i,k] = a.c ; t=2: Z[i,j] = a.b   (K = 32 = one MFMA)
// block: 128r x 128c tile, 4 waves; wave w owns rows [r0+w*32, +32) (fi=2) x 128 cols (fk=8)
__global__ __launch_bounds__(256) void scores_mfma(const u16* __restrict__ Lbf,
                                                   float* __restrict__ S,
                                                   u32* __restrict__ keys) {
    const int tid = threadIdx.x;
    const int w = tid >> 6, lane = tid & 63;
    const int l15 = lane & 15, lhi = lane >> 4;
    const int r0 = (blockIdx.x % 3) * 128, c0 = (blockIdx.x / 3) * 128;
    const int h = blockIdx.y;
    const int t = blockIdx.z;
    const int Lidx = (t == 0) ? 2 : 0;
    const int Ridx = (t == 1) ? 2 : 1;
    const u16* Lp = Lbf + ((Lidx * H + h) * N) * D;
    const u16* Rp = Lbf + ((Ridx * H + h) * N) * D;
    float* Sp = S + t * HNN + h * (N * N);
    u32* krow = keys + t * (H * N) + h * N;

    short8 a[2], b[8];
#pragma unroll
    for (int fi = 0; fi < 2; ++fi)
        a[fi] = *(const short8*)&Lp[(r0 + w * 32 + fi * 16 + l15) * D + lhi * 8];
#pragma unroll
    for (int fk = 0; fk < 8; ++fk)
        b[fk] = *(const short8*)&Rp[(c0 + fk * 16 + l15) * D + lhi * 8];

    f32x4 acc[2][8];
#pragma unroll
    for (int fi = 0; fi < 2; ++fi)
#pragma unroll
        for (int fk = 0; fk < 8; ++fk) {
            acc[fi][fk] = (f32x4){0.f, 0.f, 0.f, 0.f};
            acc[fi][fk] = __builtin_amdgcn_mfma_f32_16x16x32_bf16(a[fi], b[fk], acc[fi][fk], 0, 0, 0);
        }

#pragma unroll
    for (int fi = 0; fi < 2; ++fi) {
#pragma unroll
        for (int reg = 0; reg < 4; ++reg) {
            const int row = r0 + w * 32 + fi * 16 + lhi * 4 + reg;
            float rm = -3.0e38f;
#pragma unroll
            for (int fk = 0; fk < 8; ++fk) {
                float v = acc[fi][fk][reg] * SCALER;
                Sp[row * N + c0 + fk * 16 + l15] = v;
                rm = fmaxf(rm, v);
            }
            rm = fmaxf(rm, __shfl_xor(rm, 1));
            rm = fmaxf(rm, __shfl_xor(rm, 2));
            rm = fmaxf(rm, __shfl_xor(rm, 4));
            rm = fmaxf(rm, __shfl_xor(rm, 8));
            if (l15 == 0) atomicMax(&krow[row], fkey(rm));
        }
    }
}

// ---------------- K3: reduce mXrow keys -> mX[h] float; grid 8 x 64 ----------------
__global__ void reduce_mx_kernel(const u32* __restrict__ keys, float* __restrict__ mX) {
    const int h = blockIdx.x;
    const int lane = threadIdx.x;
    u32 m = 0;
    for (int q = lane; q < N; q += 64) m = max(m, keys[h * N + q]);
#pragma unroll
    for (int off = 32; off; off >>= 1) m = max(m, (u32)__shfl_down(m, off));
    if (lane == 0) mX[h] = fkey_dec(m);
}

// ---------------- K4: exp ----------------
// Xpack layout: [h][kt=k/16][jt=j/32][lane][8], lane = (k&15) | ((j>>3)&3)<<4  (B-frag order)
__global__ void exp_kernel(float* __restrict__ S, const float* __restrict__ mX,
                           const u32* __restrict__ keys,
                           u16* __restrict__ Xbf, u16* __restrict__ Zbf) {
    int f8 = blockIdx.x * 256 + threadIdx.x;  // 442368 total
    int flat = f8 * 8;
    int t = flat / HNN;
    int rem = flat - t * HNN;
    int h = rem / (N * N);
    int rc = rem - h * (N * N);
    int r = rc / N;
    int c = rc - r * N;
    float m = (t == 0) ? mX[h] : fkey_dec(keys[t * (H * N) + h * N + r]);
    float4 v0 = *(float4*)&S[flat];
    float4 v1 = *(float4*)&S[flat + 4];
    float e[8] = {__expf(v0.x - m), __expf(v0.y - m), __expf(v0.z - m), __expf(v0.w - m),
                  __expf(v1.x - m), __expf(v1.y - m), __expf(v1.z - m), __expf(v1.w - m)};
    if (t == 1) {
        float4 o0 = {e[0], e[1], e[2], e[3]}, o1 = {e[4], e[5], e[6], e[7]};
        *(float4*)&S[flat] = o0;
        *(float4*)&S[flat + 4] = o1;
    } else {
        short8 ov;
#pragma unroll
        for (int q = 0; q < 8; ++q) ov[q] = (short)f2bf(e[q]);
        if (t == 0) {
            const int kt = r >> 4, jt = c >> 5;
            const int lanep = (r & 15) | (((c >> 3) & 3) << 4);
            u16* dst = Xbf + (((h * 24 + kt) * 12 + jt) << 9) + lanep * 8;
            *(short8*)dst = ov;
        } else {
            u16* dst = Zbf + h * (N * N) + rc;
            *(short8*)dst = ov;
        }
    }
}

// ---------------- K5: cubic contraction via MFMA bf16, v14 (= v13 + s_setprio) ----------------
__global__ __launch_bounds__(768, 3) void cubic_mfma(
        const u16* __restrict__ Xbf, const u16* __restrict__ Zbf,
        const float* __restrict__ Yt, const float* __restrict__ vjT,
        const float* __restrict__ vkT, float* __restrict__ NumB,
        float* __restrict__ DenB) {
    const int orig = blockIdx.x;             // 0..815 (816 = 8 x 102, bijective)
    const int wg = (orig & 7) * 102 + (orig >> 3);
    const int h   = wg / 102;                // one head per XCD
    const int rem = wg - h * 102;
    const int dg  = rem / 6;                 // 0..16
    const int it6 = rem - dg * 6;            // 0..5
    const int i0  = it6 * 64;
    const bool dgden = (dg == 16);
    const int d0 = dgden ? 0 : 2 * dg;
    const int d1 = dgden ? 0 : 2 * dg + 1;
    const int tid = threadIdx.x;
    const int w = tid >> 6, lane = tid & 63;
    __shared__ u16 A_lds[2 * 64 * N];        // [t][f(48)][64][8] frag-packed
    __shared__ float red[2][12][64];
    u16* A0 = A_lds;
    u16* A1 = A_lds + 64 * N;
    const u16* Zh = Zbf + h * (N * N);
    const float* Yth = Yt + h * (N * N);
    const float* vjd0 = vjT + h * (D * N) + d0 * N;
    const float* vjd1 = vjT + h * (D * N) + d1 * N;
    const float* vkd0 = vkT + h * (D * N) + d0 * N;
    const float* vkd1 = vkT + h * (D * N) + d1 * N;

    // ---- A-prep: coalesced global reads, frag-packed LDS writes (both tiles)
    {
#pragma unroll
        for (int it = 0; it < 4; ++it) {
            const int g = it * 768 + tid;        // 0..3071
            const int row = g / 48;
            const int cb = g - row * 48;
            const int jb = cb * 8;
            const int fi = row >> 4, l15r = row & 15;
            const int js = cb >> 2, sub = cb & 3;
            const int f = fi * 12 + js;
            const int dst = f * 512 + (((l15r | (sub << 4)) ^ (f & 7)) << 3);
            short8 zv = *(const short8*)&Zh[(i0 + row) * N + jb];
            if (dgden) {
                *(short8*)&A0[dst] = zv;
                *(short8*)&A1[dst] = zv;
            } else {
                float4 p0 = *(const float4*)&vjd0[jb];
                float4 p1 = *(const float4*)&vjd0[jb + 4];
                float4 q0 = *(const float4*)&vjd1[jb];
                float4 q1 = *(const float4*)&vjd1[jb + 4];
                float v0[8] = {p0.x, p0.y, p0.z, p0.w, p1.x, p1.y, p1.z, p1.w};
                float v1[8] = {q0.x, q0.y, q0.z, q0.w, q1.x, q1.y, q1.z, q1.w};
                short8 o0, o1;
#pragma unroll
                for (int e = 0; e < 8; ++e) {
                    float zf = bf2f((u16)zv[e]);
                    o0[e] = (short)f2bf(zf * v0[e]);
                    o1[e] = (short)f2bf(zf * v1[e]);
                }
                *(short8*)&A0[dst] = o0;
                *(short8*)&A1[dst] = o1;
            }
        }
    }
    __syncthreads();

    // ---- MFMA main loop: no barriers; A and B both ping-pong prefetched
    f32x4 acc0[4][2], acc1[4][2];
#pragma unroll
    for (int fi = 0; fi < 4; ++fi)
#pragma unroll
        for (int fk = 0; fk < 2; ++fk) {
            acc0[fi][fk] = (f32x4){0.f, 0.f, 0.f, 0.f};
            acc1[fi][fk] = (f32x4){0.f, 0.f, 0.f, 0.f};
        }

    const int l15 = lane & 15;
    const int kwb = w * 32 + l15;
    const u16* Bp = Xbf + ((h * 24 + w * 2) * 12 << 9) + lane * 8;
    const int FST = 512;              // u16 per frag
    const int KT1 = 12 * 512;         // second k-tile offset

    short8 pa0[4], pa1[4], qa0[4], qa1[4];
    short8 pb[2], qb[2];
#pragma unroll
    for (int fi = 0; fi < 4; ++fi) {
        const int f = fi * 12;
        const int off = f * 512 + ((lane ^ (f & 7)) << 3);
        pa0[fi] = *(const short8*)&A0[off];
        pa1[fi] = *(const short8*)&A1[off];
    }
    pb[0] = *(const short8*)&Bp[0];
    pb[1] = *(const short8*)&Bp[KT1];

#pragma unroll
    for (int it = 0; it < 6; ++it) {
        const int js1 = 2 * it + 1;
        {   // prefetch js1 into q (A + B)
#pragma unroll
            for (int fi = 0; fi < 4; ++fi) {
                const int f = fi * 12 + js1;
                const int off = f * 512 + ((lane ^ (f & 7)) << 3);
                qa0[fi] = *(const short8*)&A0[off];
                qa1[fi] = *(const short8*)&A1[off];
            }
            qb[0] = *(const short8*)&Bp[js1 * FST];
            qb[1] = *(const short8*)&Bp[KT1 + js1 * FST];
        }
        {   // compute js0 with p
            __builtin_amdgcn_s_setprio(1);
#pragma unroll
            for (int fk = 0; fk < 2; ++fk) {
#pragma unroll
                for (int fi = 0; fi < 4; ++fi) {
                    acc0[fi][fk] = __builtin_amdgcn_mfma_f32_16x16x32_bf16(pa0[fi], pb[fk], acc0[fi][fk], 0, 0, 0);
                    acc1[fi][fk] = __builtin_amdgcn_mfma_f32_16x16x32_bf16(pa1[fi], pb[fk], acc1[fi][fk], 0, 0, 0);
                }
            }
            __builtin_amdgcn_s_setprio(0);
        }
        if (it < 5) {   // prefetch js0+2 into p
#pragma unroll
            for (int fi = 0; fi < 4; ++fi) {
                const int f = fi * 12 + js1 + 1;
                const int off = f * 512 + ((lane ^ (f & 7)) << 3);
                pa0[fi] = *(const short8*)&A0[off];
                pa1[fi] = *(const short8*)&A1[off];
            }
            pb[0] = *(const short8*)&Bp[(js1 + 1) * FST];
            pb[1] = *(const short8*)&Bp[KT1 + (js1 + 1) * FST];
        }
        {   // compute js1 with q
            __builtin_amdgcn_s_setprio(1);
#pragma unroll
            for (int fk = 0; fk < 2; ++fk) {
#pragma unroll
                for (int fi = 0; fi < 4; ++fi) {
                    acc0[fi][fk] = __builtin_amdgcn_mfma_f32_16x16x32_bf16(qa0[fi], qb[fk], acc0[fi][fk], 0, 0, 0);
                    acc1[fi][fk] = __builtin_amdgcn_mfma_f32_16x16x32_bf16(qa1[fi], qb[fk], acc1[fi][fk], 0, 0, 0);
                }
            }
            __builtin_amdgcn_s_setprio(0);
        }
    }

    // ---- epilogue: weight by YT[i,k]*vk[k,d], reduce over k; d0 then d1 (caps reg peak)
    const int rbase = (lane >> 4) << 2;
    {   // d0
        float np[4][4];
#pragma unroll
        for (int fi = 0; fi < 4; ++fi)
#pragma unroll
            for (int reg = 0; reg < 4; ++reg) np[fi][reg] = 0.f;
#pragma unroll
        for (int fk = 0; fk < 2; ++fk) {
            const int kcol = kwb + fk * 16;
            const float vkv = dgden ? 1.0f : vkd0[kcol];
#pragma unroll
            for (int fi = 0; fi < 4; ++fi) {
#pragma unroll
                for (int reg = 0; reg < 4; ++reg) {
                    const int irow = i0 + fi * 16 + rbase + reg;
                    const float wgt = Yth[irow * N + kcol] * vkv;
                    np[fi][reg] = fmaf(acc0[fi][fk][reg], wgt, np[fi][reg]);
                }
            }
        }
#pragma unroll
        for (int fi = 0; fi < 4; ++fi) {
#pragma unroll
            for (int reg = 0; reg < 4; ++reg) {
                float v = np[fi][reg];
                v += __shfl_xor(v, 1); v += __shfl_xor(v, 2);
                v += __shfl_xor(v, 4); v += __shfl_xor(v, 8);
                np[fi][reg] = v;
            }
        }
        if (l15 == 0) {
#pragma unroll
            for (int fi = 0; fi < 4; ++fi)
#pragma unroll
                for (int reg = 0; reg < 4; ++reg)
                    red[0][w][fi * 16 + rbase + reg] = np[fi][reg];
        }
    }
    {   // d1
        float np[4][4];
#pragma unroll
        for (int fi = 0; fi < 4; ++fi)
#pragma unroll
            for (int reg = 0; reg < 4; ++reg) np[fi][reg] = 0.f;
#pragma unroll
        for (int fk = 0; fk < 2; ++fk) {
            const int kcol = kwb + fk * 16;
            const float vkv = dgden ? 1.0f : vkd1[kcol];
#pragma unroll
            for (int fi = 0; fi < 4; ++fi) {
#pragma unroll
                for (int reg = 0; reg < 4; ++reg) {
                    const int irow = i0 + fi * 16 + rbase + reg;
                    const float wgt = Yth[irow * N + kcol] * vkv;
                    np[fi][reg] = fmaf(acc1[fi][fk][reg], wgt, np[fi][reg]);
                }
            }
        }
#pragma unroll
        for (int fi = 0; fi < 4; ++fi) {
#pragma unroll
            for (int reg = 0; reg < 4; ++reg) {
                float v = np[fi][reg];
                v += __shfl_xor(v, 1); v += __shfl_xor(v, 2);
                v += __shfl_xor(v, 4); v += __shfl_xor(v, 8);
                np[fi][reg] = v;
            }
        }
        if (l15 == 0) {
#pragma unroll
            for (int fi = 0; fi < 4; ++fi)
#pragma unroll
                for (int reg = 0; reg < 4; ++reg)
                    red[1][w][fi * 16 + rbase + reg] = np[fi][reg];
        }
    }
    __syncthreads();
    if (tid < 64) {
        float s = 0.f;
#pragma unroll
        for (int ww = 0; ww < 12; ++ww) s += red[0][ww][tid];
        if (!dgden) NumB[h * (N * D) + (i0 + tid) * D + 2 * dg] = s;
        else        DenB[h * N + i0 + tid] = s;
    } else if (tid < 128 && !dgden) {
        const int i = tid - 64;
        float s = 0.f;
#pragma unroll
        for (int ww = 0; ww < 12; ++ww) s += red[1][ww][i];
        NumB[h * (N * D) + (i0 + i) * D + 2 * dg + 1] = s;
    }
}

// ---------------- K6: normalize + fp32 output [n, h*D+d] ----------------
__global__ void out_kernel(const float* __restrict__ NumB, const float* __restrict__ DenB,
                           float* __restrict__ out) {
    int idx = blockIdx.x * 256 + threadIdx.x;  // 0..98303
    int n = idx >> 8;
    int ch = idx & 255;
    int hh = ch >> 5, d = ch & 31;
    float v = NumB[hh * (N * D) + n * D + d] / (DenB[hh * N + n] + EPS);
    out[idx] = v;
}

extern "C" void kernel_launch(void* const* d_in, const int* in_sizes, int n_in,
                              void* d_out, int out_size, void* d_ws, size_t ws_size,
                              hipStream_t stream) {
    const float* hs = (const float*)d_in[0];
    const float* W  = (const float*)d_in[1];
    float* ws = (float*)d_ws;
    float* proj  = ws + PROJ_OFF;
    float* S     = ws + S_OFF;
    float* projT = ws + VJT_OFF;    // vj rows, then vk rows at +H*D*N
    float* mX    = ws + MX_OFF;
    float* NumB  = ws + NUM_OFF;
    float* DenB  = ws + DEN_OFF;
    u16*   Xbf   = (u16*)(ws + XBF_OFF);
    u16*   Zbf   = (u16*)(ws + ZBF_OFF);
    u32*   keys  = (u32*)(ws + KEYS_OFF);   // 3*H*N keys
    u16*   Lbf   = (u16*)(ws + LBF_OFF);    // bf16 a,b,c
    float* out = (float*)d_out;

    hipMemsetAsync(keys, 0, 3 * H * N * sizeof(u32), stream);
    proj_kernel<<<dim3(20, 6), 256, 0, stream>>>(hs, W, proj, projT, Lbf);
    scores_mfma<<<dim3(9, 8, 3), 256, 0, stream>>>(Lbf, S, keys);
    reduce_mx_kernel<<<8, 64, 0, stream>>>(keys, mX);
    exp_kernel<<<1728, 256, 0, stream>>>(S, mX, keys, Xbf, Zbf);
    cubic_mfma<<<dim3(816), 768, 0, stream>>>(Xbf, Zbf, S + HNN, ws + VJT_OFF,
                                              ws + VKT_OFF, NumB, DenB);
    out_kernel<<<(H * N * D) / 256, 256, 0, stream>>>(NumB, DenB, out);
}

// Round 17
// 94.281 us; speedup vs baseline: 1.1750x; 1.0684x over previous
//
#include <hip/hip_runtime.h>
#include <hip/hip_bf16.h>

typedef unsigned short u16;
typedef unsigned int u32;
typedef __attribute__((ext_vector_type(8))) short short8;
typedef __attribute__((ext_vector_type(4))) float f32x4;

#define H 8
#define N 384
#define D 32
#define CIN 256
#define HNN (H * N * N)
#define SCALER 0.17677669529663687f
#define EPS 1e-9f

// workspace float offsets
#define PROJ_OFF 0u              // 5*H*N*D = 491520: a,b,c,vj,vk as [5][H][N][D]
#define S_OFF    491520u         // 3*H*N*N: t=0 XT[k][j], t=1 YT[i][k], t=2 Z[i][j]
#define VJT_OFF  4030464u        // H*D*N = 98304: vj transposed [h][d][n]
#define VKT_OFF  4128768u        // H*D*N
#define MX_OFF   4227072u        // 8 floats (decoded global max of X per head)
#define NUM_OFF  4233224u        // H*N*D
#define DEN_OFF  4331528u        // H*N
#define XBF_OFF  4334600u        // ushort[H*N*N]: X packed in MFMA-frag order
#define ZBF_OFF  4924424u        // ushort[H*N*N] (Z bf16, row-major)
#define KEYS_OFF 5514248u        // u32 keys: mXrowK[H*N], mYK[H*N], mZK[H*N] (memset 0 per call)
#define LBF_OFF  5523464u        // u16[3*H*N*D]: bf16 copies of a,b,c for scores MFMA

__device__ inline float bf2f(u16 u) {
    union { unsigned int x; float f; } c; c.x = ((unsigned int)u) << 16; return c.f;
}
__device__ inline u16 f2bf(float f) {
    unsigned int x = __float_as_uint(f);
    return (u16)((x + 0x7FFFu + ((x >> 16) & 1u)) >> 16);
}
// order-preserving float->uint key (exact; atomicMax-able); 0 is below all keys
__device__ inline u32 fkey(float f) {
    u32 u = __float_as_uint(f);
    return (u >> 31) ? ~u : (u | 0x80000000u);
}
__device__ inline float fkey_dec(u32 k) {
    return (k >> 31) ? __uint_as_float(k ^ 0x80000000u) : __uint_as_float(~k);
}

// ---------------- K1: projection GEMM  wx[n,m] = sum_k hs[n,k]*W[m,k] ----------------
// also emits bf16 copies of a,b,c (s<3) for the MFMA scores kernel
__global__ __launch_bounds__(256) void proj_kernel(const float* __restrict__ hs,
                                                   const float* __restrict__ W,
                                                   float* __restrict__ proj,
                                                   float* __restrict__ projT,
                                                   u16* __restrict__ Lbf) {
    __shared__ float hs_s[64][68];
    __shared__ float w_s[64][68];
    const int tid = threadIdx.x;
    const int tx = tid & 15, ty = tid >> 4;
    const int m0 = blockIdx.x * 64, n0 = blockIdx.y * 64;
    float acc[4][4] = {};
    for (int k0 = 0; k0 < CIN; k0 += 64) {
        __syncthreads();
#pragma unroll
        for (int rep = 0; rep < 4; ++rep) {
            int lin = rep * 1024 + tid * 4;
            int rl = lin >> 6, kl = lin & 63;
            float4 hv = *(const float4*)&hs[(n0 + rl) * CIN + k0 + kl];
            hs_s[kl + 0][rl] = hv.x; hs_s[kl + 1][rl] = hv.y;
            hs_s[kl + 2][rl] = hv.z; hs_s[kl + 3][rl] = hv.w;
            float4 wv = *(const float4*)&W[(m0 + rl) * CIN + k0 + kl];
            w_s[kl + 0][rl] = wv.x; w_s[kl + 1][rl] = wv.y;
            w_s[kl + 2][rl] = wv.z; w_s[kl + 3][rl] = wv.w;
        }
        __syncthreads();
#pragma unroll 16
        for (int kk = 0; kk < 64; ++kk) {
            float4 a4 = *(const float4*)&hs_s[kk][ty * 4];
            float4 b4 = *(const float4*)&w_s[kk][tx * 4];
            float av[4] = {a4.x, a4.y, a4.z, a4.w};
            float bv[4] = {b4.x, b4.y, b4.z, b4.w};
#pragma unroll
            for (int a_ = 0; a_ < 4; ++a_) {
#pragma unroll
                for (int b_ = 0; b_ < 4; ++b_) {
                    acc[a_][b_] = fmaf(av[a_], bv[b_], acc[a_][b_]);
                }
            }
        }
    }
#pragma unroll
    for (int a_ = 0; a_ < 4; ++a_) {
        int n = n0 + ty * 4 + a_;
#pragma unroll
        for (int b_ = 0; b_ < 4; ++b_) {
            int m = m0 + tx * 4 + b_;
            int s = m >> 8, hh = (m >> 5) & 7, d = m & 31;
            proj[s * (H * N * D) + hh * (N * D) + n * D + d] = acc[a_][b_];
            if (s >= 3) projT[(s - 3) * (H * D * N) + hh * (D * N) + d * N + n] = acc[a_][b_];
            else        Lbf[((s * H + hh) * N + n) * D + d] = f2bf(acc[a_][b_]);
        }
    }
}

// ---------------- K2: scores via MFMA bf16 + fused row-max atomics ----------------
// t=0: XT[k,j] = c.b ; t=1: YT[i,k] = a.c ; t=2: Z[i,j] = a.b   (K = 32 = one MFMA)
// block: 128r x 128c tile, 4 waves; wave w owns rows [r0+w*32, +32) (fi=2) x 128 cols (fk=8)
__global__ __launch_bounds__(256) void scores_mfma(const u16* __restrict__ Lbf,
                                                   float* __restrict__ S,
                                                   u32* __restrict__ keys) {
    const int tid = threadIdx.x;
    const int w = tid >> 6, lane = tid & 63;
    const int l15 = lane & 15, lhi = lane >> 4;
    const int r0 = (blockIdx.x % 3) * 128, c0 = (blockIdx.x / 3) * 128;
    const int h = blockIdx.y;
    const int t = blockIdx.z;
    const int Lidx = (t == 0) ? 2 : 0;
    const int Ridx = (t == 1) ? 2 : 1;
    const u16* Lp = Lbf + ((Lidx * H + h) * N) * D;
    const u16* Rp = Lbf + ((Ridx * H + h) * N) * D;
    float* Sp = S + t * HNN + h * (N * N);
    u32* krow = keys + t * (H * N) + h * N;

    short8 a[2], b[8];
#pragma unroll
    for (int fi = 0; fi < 2; ++fi)
        a[fi] = *(const short8*)&Lp[(r0 + w * 32 + fi * 16 + l15) * D + lhi * 8];
#pragma unroll
    for (int fk = 0; fk < 8; ++fk)
        b[fk] = *(const short8*)&Rp[(c0 + fk * 16 + l15) * D + lhi * 8];

    f32x4 acc[2][8];
#pragma unroll
    for (int fi = 0; fi < 2; ++fi)
#pragma unroll
        for (int fk = 0; fk < 8; ++fk) {
            acc[fi][fk] = (f32x4){0.f, 0.f, 0.f, 0.f};
            acc[fi][fk] = __builtin_amdgcn_mfma_f32_16x16x32_bf16(a[fi], b[fk], acc[fi][fk], 0, 0, 0);
        }

#pragma unroll
    for (int fi = 0; fi < 2; ++fi) {
#pragma unroll
        for (int reg = 0; reg < 4; ++reg) {
            const int row = r0 + w * 32 + fi * 16 + lhi * 4 + reg;
            float rm = -3.0e38f;
#pragma unroll
            for (int fk = 0; fk < 8; ++fk) {
                float v = acc[fi][fk][reg] * SCALER;
                Sp[row * N + c0 + fk * 16 + l15] = v;
                rm = fmaxf(rm, v);
            }
            rm = fmaxf(rm, __shfl_xor(rm, 1));
            rm = fmaxf(rm, __shfl_xor(rm, 2));
            rm = fmaxf(rm, __shfl_xor(rm, 4));
            rm = fmaxf(rm, __shfl_xor(rm, 8));
            if (l15 == 0) atomicMax(&krow[row], fkey(rm));
        }
    }
}

// ---------------- K3: reduce mXrow keys -> mX[h] float; grid 8 x 64 ----------------
__global__ void reduce_mx_kernel(const u32* __restrict__ keys, float* __restrict__ mX) {
    const int h = blockIdx.x;
    const int lane = threadIdx.x;
    u32 m = 0;
    for (int q = lane; q < N; q += 64) m = max(m, keys[h * N + q]);
#pragma unroll
    for (int off = 32; off; off >>= 1) m = max(m, (u32)__shfl_down(m, off));
    if (lane == 0) mX[h] = fkey_dec(m);
}

// ---------------- K4: exp ----------------
// Xpack layout: [h][kt=k/16][jt=j/32][lane][8], lane = (k&15) | ((j>>3)&3)<<4  (B-frag order)
__global__ void exp_kernel(float* __restrict__ S, const float* __restrict__ mX,
                           const u32* __restrict__ keys,
                           u16* __restrict__ Xbf, u16* __restrict__ Zbf) {
    int f8 = blockIdx.x * 256 + threadIdx.x;  // 442368 total
    int flat = f8 * 8;
    int t = flat / HNN;
    int rem = flat - t * HNN;
    int h = rem / (N * N);
    int rc = rem - h * (N * N);
    int r = rc / N;
    int c = rc - r * N;
    float m = (t == 0) ? mX[h] : fkey_dec(keys[t * (H * N) + h * N + r]);
    float4 v0 = *(float4*)&S[flat];
    float4 v1 = *(float4*)&S[flat + 4];
    float e[8] = {__expf(v0.x - m), __expf(v0.y - m), __expf(v0.z - m), __expf(v0.w - m),
                  __expf(v1.x - m), __expf(v1.y - m), __expf(v1.z - m), __expf(v1.w - m)};
    if (t == 1) {
        float4 o0 = {e[0], e[1], e[2], e[3]}, o1 = {e[4], e[5], e[6], e[7]};
        *(float4*)&S[flat] = o0;
        *(float4*)&S[flat + 4] = o1;
    } else {
        short8 ov;
#pragma unroll
        for (int q = 0; q < 8; ++q) ov[q] = (short)f2bf(e[q]);
        if (t == 0) {
            const int kt = r >> 4, jt = c >> 5;
            const int lanep = (r & 15) | (((c >> 3) & 3) << 4);
            u16* dst = Xbf + (((h * 24 + kt) * 12 + jt) << 9) + lanep * 8;
            *(short8*)dst = ov;
        } else {
            u16* dst = Zbf + h * (N * N) + rc;
            *(short8*)dst = ov;
        }
    }
}

// ---------------- K5: cubic contraction via MFMA bf16, v15 (32i blocks, 2 blocks/CU) ----------------
// block = (h, i-tile of 32, d-group of 2). 384 thr = 6 waves; wave w owns k in [w*64,+64)
// (fk=4 packed-B frags), fi=2 per d-tile. Per js: 4 A LDS reads + 4 coalesced B loads +
// 16 MFMAs. Regs ~120 <= 170 (384,3) -> 12 waves/CU = 2 co-resident blocks: prep/epilogue
// of one block overlaps the other's main loop; tail quantum halves (1632 blocks).
__global__ __launch_bounds__(384, 3) void cubic_mfma(
        const u16* __restrict__ Xbf, const u16* __restrict__ Zbf,
        const float* __restrict__ Yt, const float* __restrict__ vjT,
        const float* __restrict__ vkT, float* __restrict__ NumB,
        float* __restrict__ DenB) {
    const int orig = blockIdx.x;             // 0..1631 (1632 = 8 x 204, bijective)
    const int wg = (orig & 7) * 204 + (orig >> 3);
    const int h   = wg / 204;                // one head per XCD
    const int rem = wg - h * 204;
    const int dg  = rem / 12;                // 0..16
    const int it12 = rem - dg * 12;          // 0..11
    const int i0  = it12 * 32;
    const bool dgden = (dg == 16);
    const int d0 = dgden ? 0 : 2 * dg;
    const int d1 = dgden ? 0 : 2 * dg + 1;
    const int tid = threadIdx.x;
    const int w = tid >> 6, lane = tid & 63;
    __shared__ u16 A_lds[2 * 32 * N];        // [t][f(24)][64][8] frag-packed (48 KB)
    __shared__ float red[2][6][32];
    u16* A0 = A_lds;
    u16* A1 = A_lds + 32 * N;
    const u16* Zh = Zbf + h * (N * N);
    const float* Yth = Yt + h * (N * N);
    const float* vjd0 = vjT + h * (D * N) + d0 * N;
    const float* vjd1 = vjT + h * (D * N) + d1 * N;
    const float* vkd0 = vkT + h * (D * N) + d0 * N;
    const float* vkd1 = vkT + h * (D * N) + d1 * N;

    // ---- A-prep: coalesced global reads, frag-packed LDS writes (both tiles)
    // 1536 chunks(short8) per tile; 4 iters x 384 thr
    {
#pragma unroll
        for (int it = 0; it < 4; ++it) {
            const int g = it * 384 + tid;        // 0..1535
            const int row = g / 48;              // 0..31
            const int cb = g - row * 48;
            const int jb = cb * 8;
            const int fi = row >> 4, l15r = row & 15;
            const int js = cb >> 2, sub = cb & 3;
            const int f = fi * 12 + js;          // 0..23
            const int dst = f * 512 + (((l15r | (sub << 4)) ^ (f & 7)) << 3);
            short8 zv = *(const short8*)&Zh[(i0 + row) * N + jb];
            if (dgden) {
                *(short8*)&A0[dst] = zv;
                *(short8*)&A1[dst] = zv;
            } else {
                float4 p0 = *(const float4*)&vjd0[jb];
                float4 p1 = *(const float4*)&vjd0[jb + 4];
                float4 q0 = *(const float4*)&vjd1[jb];
                float4 q1 = *(const float4*)&vjd1[jb + 4];
                float v0[8] = {p0.x, p0.y, p0.z, p0.w, p1.x, p1.y, p1.z, p1.w};
                float v1[8] = {q0.x, q0.y, q0.z, q0.w, q1.x, q1.y, q1.z, q1.w};
                short8 o0, o1;
#pragma unroll
                for (int e = 0; e < 8; ++e) {
                    float zf = bf2f((u16)zv[e]);
                    o0[e] = (short)f2bf(zf * v0[e]);
                    o1[e] = (short)f2bf(zf * v1[e]);
                }
                *(short8*)&A0[dst] = o0;
                *(short8*)&A1[dst] = o1;
            }
        }
    }
    __syncthreads();

    // ---- MFMA main loop: no barriers, k held in accumulators
    f32x4 acc0[2][4], acc1[2][4];
#pragma unroll
    for (int fi = 0; fi < 2; ++fi)
#pragma unroll
        for (int fk = 0; fk < 4; ++fk) {
            acc0[fi][fk] = (f32x4){0.f, 0.f, 0.f, 0.f};
            acc1[fi][fk] = (f32x4){0.f, 0.f, 0.f, 0.f};
        }

    const int l15 = lane & 15;
    // packed-B: wave w covers k-tiles 4w..4w+3; frag (kt, jt) at (kt*12+jt)*512
    const u16* Bp = Xbf + ((h * 24 + w * 4) * 12 << 9) + lane * 8;
    const int KTS = 12 * 512;         // k-tile stride (u16)

#pragma unroll
    for (int js = 0; js < 12; ++js) {
        short8 a0[2], a1[2];
#pragma unroll
        for (int fi = 0; fi < 2; ++fi) {
            const int f = fi * 12 + js;
            const int off = f * 512 + ((lane ^ (f & 7)) << 3);
            a0[fi] = *(const short8*)&A0[off];
            a1[fi] = *(const short8*)&A1[off];
        }
        short8 b[4];
#pragma unroll
        for (int fk = 0; fk < 4; ++fk)
            b[fk] = *(const short8*)&Bp[fk * KTS + js * 512];
        __builtin_amdgcn_s_setprio(1);
#pragma unroll
        for (int fk = 0; fk < 4; ++fk) {
#pragma unroll
            for (int fi = 0; fi < 2; ++fi) {
                acc0[fi][fk] = __builtin_amdgcn_mfma_f32_16x16x32_bf16(a0[fi], b[fk], acc0[fi][fk], 0, 0, 0);
                acc1[fi][fk] = __builtin_amdgcn_mfma_f32_16x16x32_bf16(a1[fi], b[fk], acc1[fi][fk], 0, 0, 0);
            }
        }
        __builtin_amdgcn_s_setprio(0);
    }

    // ---- epilogue: weight by YT[i,k]*vk[k,d], reduce over k; d0 then d1
    const int rbase = (lane >> 4) << 2;
    {   // d0
        float np[2][4];
#pragma unroll
        for (int fi = 0; fi < 2; ++fi)
#pragma unroll
            for (int reg = 0; reg < 4; ++reg) np[fi][reg] = 0.f;
#pragma unroll
        for (int fk = 0; fk < 4; ++fk) {
            const int kcol = w * 64 + fk * 16 + l15;
            const float vkv = dgden ? 1.0f : vkd0[kcol];
#pragma unroll
            for (int fi = 0; fi < 2; ++fi) {
#pragma unroll
                for (int reg = 0; reg < 4; ++reg) {
                    const int irow = i0 + fi * 16 + rbase + reg;
                    const float wgt = Yth[irow * N + kcol] * vkv;
                    np[fi][reg] = fmaf(acc0[fi][fk][reg], wgt, np[fi][reg]);
                }
            }
        }
#pragma unroll
        for (int fi = 0; fi < 2; ++fi) {
#pragma unroll
            for (int reg = 0; reg < 4; ++reg) {
                float v = np[fi][reg];
                v += __shfl_xor(v, 1); v += __shfl_xor(v, 2);
                v += __shfl_xor(v, 4); v += __shfl_xor(v, 8);
                np[fi][reg] = v;
            }
        }
        if (l15 == 0) {
#pragma unroll
            for (int fi = 0; fi < 2; ++fi)
#pragma unroll
                for (int reg = 0; reg < 4; ++reg)
                    red[0][w][fi * 16 + rbase + reg] = np[fi][reg];
        }
    }
    {   // d1
        float np[2][4];
#pragma unroll
        for (int fi = 0; fi < 2; ++fi)
#pragma unroll
            for (int reg = 0; reg < 4; ++reg) np[fi][reg] = 0.f;
#pragma unroll
        for (int fk = 0; fk < 4; ++fk) {
            const int kcol = w * 64 + fk * 16 + l15;
            const float vkv = dgden ? 1.0f : vkd1[kcol];
#pragma unroll
            for (int fi = 0; fi < 2; ++fi) {
#pragma unroll
                for (int reg = 0; reg < 4; ++reg) {
                    const int irow = i0 + fi * 16 + rbase + reg;
                    const float wgt = Yth[irow * N + kcol] * vkv;
                    np[fi][reg] = fmaf(acc1[fi][fk][reg], wgt, np[fi][reg]);
                }
            }
        }
#pragma unroll
        for (int fi = 0; fi < 2; ++fi) {
#pragma unroll
            for (int reg = 0; reg < 4; ++reg) {
                float v = np[fi][reg];
                v += __shfl_xor(v, 1); v += __shfl_xor(v, 2);
                v += __shfl_xor(v, 4); v += __shfl_xor(v, 8);
                np[fi][reg] = v;
            }
        }
        if (l15 == 0) {
#pragma unroll
            for (int fi = 0; fi < 2; ++fi)
#pragma unroll
                for (int reg = 0; reg < 4; ++reg)
                    red[1][w][fi * 16 + rbase + reg] = np[fi][reg];
        }
    }
    __syncthreads();
    if (tid < 32) {
        float s = 0.f;
#pragma unroll
        for (int ww = 0; ww < 6; ++ww) s += red[0][ww][tid];
        if (!dgden) NumB[h * (N * D) + (i0 + tid) * D + 2 * dg] = s;
        else        DenB[h * N + i0 + tid] = s;
    } else if (tid < 64 && !dgden) {
        const int i = tid - 32;
        float s = 0.f;
#pragma unroll
        for (int ww = 0; ww < 6; ++ww) s += red[1][ww][i];
        NumB[h * (N * D) + (i0 + i) * D + 2 * dg + 1] = s;
    }
}

// ---------------- K6: normalize + fp32 output [n, h*D+d] ----------------
__global__ void out_kernel(const float* __restrict__ NumB, const float* __restrict__ DenB,
                           float* __restrict__ out) {
    int idx = blockIdx.x * 256 + threadIdx.x;  // 0..98303
    int n = idx >> 8;
    int ch = idx & 255;
    int hh = ch >> 5, d = ch & 31;
    float v = NumB[hh * (N * D) + n * D + d] / (DenB[hh * N + n] + EPS);
    out[idx] = v;
}

extern "C" void kernel_launch(void* const* d_in, const int* in_sizes, int n_in,
                              void* d_out, int out_size, void* d_ws, size_t ws_size,
                              hipStream_t stream) {
    const float* hs = (const float*)d_in[0];
    const float* W  = (const float*)d_in[1];
    float* ws = (float*)d_ws;
    float* proj  = ws + PROJ_OFF;
    float* S     = ws + S_OFF;
    float* projT = ws + VJT_OFF;    // vj rows, then vk rows at +H*D*N
    float* mX    = ws + MX_OFF;
    float* NumB  = ws + NUM_OFF;
    float* DenB  = ws + DEN_OFF;
    u16*   Xbf   = (u16*)(ws + XBF_OFF);
    u16*   Zbf   = (u16*)(ws + ZBF_OFF);
    u32*   keys  = (u32*)(ws + KEYS_OFF);   // 3*H*N keys
    u16*   Lbf   = (u16*)(ws + LBF_OFF);    // bf16 a,b,c
    float* out = (float*)d_out;

    hipMemsetAsync(keys, 0, 3 * H * N * sizeof(u32), stream);
    proj_kernel<<<dim3(20, 6), 256, 0, stream>>>(hs, W, proj, projT, Lbf);
    scores_mfma<<<dim3(9, 8, 3), 256, 0, stream>>>(Lbf, S, keys);
    reduce_mx_kernel<<<8, 64, 0, stream>>>(keys, mX);
    exp_kernel<<<1728, 256, 0, stream>>>(S, mX, keys, Xbf, Zbf);
    cubic_mfma<<<dim3(1632), 384, 0, stream>>>(Xbf, Zbf, S + HNN, ws + VJT_OFF,
                                               ws + VKT_OFF, NumB, DenB);
    out_kernel<<<(H * N * D) / 256, 256, 0, stream>>>(NumB, DenB, out);
}

// Round 18
// 93.435 us; speedup vs baseline: 1.1856x; 1.0091x over previous
//
#include <hip/hip_runtime.h>
#include <hip/hip_bf16.h>

typedef unsigned short u16;
typedef unsigned int u32;
typedef __attribute__((ext_vector_type(8))) short short8;
typedef __attribute__((ext_vector_type(4))) float f32x4;

#define H 8
#define N 384
#define D 32
#define CIN 256
#define HNN (H * N * N)
#define SCALER 0.17677669529663687f
#define EPS 1e-9f

// workspace float offsets
#define PROJ_OFF 0u              // 5*H*N*D = 491520: a,b,c,vj,vk as [5][H][N][D]
#define S_OFF    491520u         // 3*H*N*N: t=0 XT[k][j], t=1 YT[i][k], t=2 Z[i][j]
#define VJT_OFF  4030464u        // H*D*N = 98304: vj transposed [h][d][n]
#define VKT_OFF  4128768u        // H*D*N
#define MX_OFF   4227072u        // 8 floats (decoded global max of X per head)
#define NUM_OFF  4233224u        // H*N*D
#define DEN_OFF  4331528u        // H*N
#define XBF_OFF  4334600u        // ushort[H*N*N]: X packed in MFMA-frag order
#define ZBF_OFF  4924424u        // ushort[H*N*N] (Z bf16, row-major)
#define KEYS_OFF 5514248u        // u32 keys: mXrowK[H*N], mYK[H*N], mZK[H*N] (memset 0 per call)
#define LBF_OFF  5523464u        // u16[3*H*N*D]: bf16 copies of a,b,c for scores MFMA

__device__ inline float bf2f(u16 u) {
    union { unsigned int x; float f; } c; c.x = ((unsigned int)u) << 16; return c.f;
}
__device__ inline u16 f2bf(float f) {
    unsigned int x = __float_as_uint(f);
    return (u16)((x + 0x7FFFu + ((x >> 16) & 1u)) >> 16);
}
// order-preserving float->uint key (exact; atomicMax-able); 0 is below all keys
__device__ inline u32 fkey(float f) {
    u32 u = __float_as_uint(f);
    return (u >> 31) ? ~u : (u | 0x80000000u);
}
__device__ inline float fkey_dec(u32 k) {
    return (k >> 31) ? __uint_as_float(k ^ 0x80000000u) : __uint_as_float(~k);
}

// ---------------- K1: projection GEMM  wx[n,m] = sum_k hs[n,k]*W[m,k] ----------------
// also emits bf16 copies of a,b,c (s<3) for the MFMA scores kernel
__global__ __launch_bounds__(256) void proj_kernel(const float* __restrict__ hs,
                                                   const float* __restrict__ W,
                                                   float* __restrict__ proj,
                                                   float* __restrict__ projT,
                                                   u16* __restrict__ Lbf) {
    __shared__ float hs_s[64][68];
    __shared__ float w_s[64][68];
    const int tid = threadIdx.x;
    const int tx = tid & 15, ty = tid >> 4;
    const int m0 = blockIdx.x * 64, n0 = blockIdx.y * 64;
    float acc[4][4] = {};
    for (int k0 = 0; k0 < CIN; k0 += 64) {
        __syncthreads();
#pragma unroll
        for (int rep = 0; rep < 4; ++rep) {
            int lin = rep * 1024 + tid * 4;
            int rl = lin >> 6, kl = lin & 63;
            float4 hv = *(const float4*)&hs[(n0 + rl) * CIN + k0 + kl];
            hs_s[kl + 0][rl] = hv.x; hs_s[kl + 1][rl] = hv.y;
            hs_s[kl + 2][rl] = hv.z; hs_s[kl + 3][rl] = hv.w;
            float4 wv = *(const float4*)&W[(m0 + rl) * CIN + k0 + kl];
            w_s[kl + 0][rl] = wv.x; w_s[kl + 1][rl] = wv.y;
            w_s[kl + 2][rl] = wv.z; w_s[kl + 3][rl] = wv.w;
        }
        __syncthreads();
#pragma unroll 16
        for (int kk = 0; kk < 64; ++kk) {
            float4 a4 = *(const float4*)&hs_s[kk][ty * 4];
            float4 b4 = *(const float4*)&w_s[kk][tx * 4];
            float av[4] = {a4.x, a4.y, a4.z, a4.w};
            float bv[4] = {b4.x, b4.y, b4.z, b4.w};
#pragma unroll
            for (int a_ = 0; a_ < 4; ++a_) {
#pragma unroll
                for (int b_ = 0; b_ < 4; ++b_) {
                    acc[a_][b_] = fmaf(av[a_], bv[b_], acc[a_][b_]);
                }
            }
        }
    }
#pragma unroll
    for (int a_ = 0; a_ < 4; ++a_) {
        int n = n0 + ty * 4 + a_;
#pragma unroll
        for (int b_ = 0; b_ < 4; ++b_) {
            int m = m0 + tx * 4 + b_;
            int s = m >> 8, hh = (m >> 5) & 7, d = m & 31;
            proj[s * (H * N * D) + hh * (N * D) + n * D + d] = acc[a_][b_];
            if (s >= 3) projT[(s - 3) * (H * D * N) + hh * (D * N) + d * N + n] = acc[a_][b_];
            else        Lbf[((s * H + hh) * N + n) * D + d] = f2bf(acc[a_][b_]);
        }
    }
}

// ---------------- K2: scores via MFMA bf16 + fused row-max atomics ----------------
// t=0: XT[k,j] = c.b ; t=1: YT[i,k] = a.c ; t=2: Z[i,j] = a.b   (K = 32 = one MFMA)
// block: 128r x 128c tile, 4 waves; wave w owns rows [r0+w*32, +32) (fi=2) x 128 cols (fk=8)
__global__ __launch_bounds__(256) void scores_mfma(const u16* __restrict__ Lbf,
                                                   float* __restrict__ S,
                                                   u32* __restrict__ keys) {
    const int tid = threadIdx.x;
    const int w = tid >> 6, lane = tid & 63;
    const int l15 = lane & 15, lhi = lane >> 4;
    const int r0 = (blockIdx.x % 3) * 128, c0 = (blockIdx.x / 3) * 128;
    const int h = blockIdx.y;
    const int t = blockIdx.z;
    const int Lidx = (t == 0) ? 2 : 0;
    const int Ridx = (t == 1) ? 2 : 1;
    const u16* Lp = Lbf + ((Lidx * H + h) * N) * D;
    const u16* Rp = Lbf + ((Ridx * H + h) * N) * D;
    float* Sp = S + t * HNN + h * (N * N);
    u32* krow = keys + t * (H * N) + h * N;

    short8 a[2], b[8];
#pragma unroll
    for (int fi = 0; fi < 2; ++fi)
        a[fi] = *(const short8*)&Lp[(r0 + w * 32 + fi * 16 + l15) * D + lhi * 8];
#pragma unroll
    for (int fk = 0; fk < 8; ++fk)
        b[fk] = *(const short8*)&Rp[(c0 + fk * 16 + l15) * D + lhi * 8];

    f32x4 acc[2][8];
#pragma unroll
    for (int fi = 0; fi < 2; ++fi)
#pragma unroll
        for (int fk = 0; fk < 8; ++fk) {
            acc[fi][fk] = (f32x4){0.f, 0.f, 0.f, 0.f};
            acc[fi][fk] = __builtin_amdgcn_mfma_f32_16x16x32_bf16(a[fi], b[fk], acc[fi][fk], 0, 0, 0);
        }

#pragma unroll
    for (int fi = 0; fi < 2; ++fi) {
#pragma unroll
        for (int reg = 0; reg < 4; ++reg) {
            const int row = r0 + w * 32 + fi * 16 + lhi * 4 + reg;
            float rm = -3.0e38f;
#pragma unroll
            for (int fk = 0; fk < 8; ++fk) {
                float v = acc[fi][fk][reg] * SCALER;
                Sp[row * N + c0 + fk * 16 + l15] = v;
                rm = fmaxf(rm, v);
            }
            rm = fmaxf(rm, __shfl_xor(rm, 1));
            rm = fmaxf(rm, __shfl_xor(rm, 2));
            rm = fmaxf(rm, __shfl_xor(rm, 4));
            rm = fmaxf(rm, __shfl_xor(rm, 8));
            if (l15 == 0) atomicMax(&krow[row], fkey(rm));
        }
    }
}

// ---------------- K3: reduce mXrow keys -> mX[h] float; grid 8 x 64 ----------------
__global__ void reduce_mx_kernel(const u32* __restrict__ keys, float* __restrict__ mX) {
    const int h = blockIdx.x;
    const int lane = threadIdx.x;
    u32 m = 0;
    for (int q = lane; q < N; q += 64) m = max(m, keys[h * N + q]);
#pragma unroll
    for (int off = 32; off; off >>= 1) m = max(m, (u32)__shfl_down(m, off));
    if (lane == 0) mX[h] = fkey_dec(m);
}

// ---------------- K4: exp ----------------
// Xpack layout: [h][kt=k/16][jt=j/32][lane][8], lane = (k&15) | ((j>>3)&3)<<4  (B-frag order)
__global__ void exp_kernel(float* __restrict__ S, const float* __restrict__ mX,
                           const u32* __restrict__ keys,
                           u16* __restrict__ Xbf, u16* __restrict__ Zbf) {
    int f8 = blockIdx.x * 256 + threadIdx.x;  // 442368 total
    int flat = f8 * 8;
    int t = flat / HNN;
    int rem = flat - t * HNN;
    int h = rem / (N * N);
    int rc = rem - h * (N * N);
    int r = rc / N;
    int c = rc - r * N;
    float m = (t == 0) ? mX[h] : fkey_dec(keys[t * (H * N) + h * N + r]);
    float4 v0 = *(float4*)&S[flat];
    float4 v1 = *(float4*)&S[flat + 4];
    float e[8] = {__expf(v0.x - m), __expf(v0.y - m), __expf(v0.z - m), __expf(v0.w - m),
                  __expf(v1.x - m), __expf(v1.y - m), __expf(v1.z - m), __expf(v1.w - m)};
    if (t == 1) {
        float4 o0 = {e[0], e[1], e[2], e[3]}, o1 = {e[4], e[5], e[6], e[7]};
        *(float4*)&S[flat] = o0;
        *(float4*)&S[flat + 4] = o1;
    } else {
        short8 ov;
#pragma unroll
        for (int q = 0; q < 8; ++q) ov[q] = (short)f2bf(e[q]);
        if (t == 0) {
            const int kt = r >> 4, jt = c >> 5;
            const int lanep = (r & 15) | (((c >> 3) & 3) << 4);
            u16* dst = Xbf + (((h * 24 + kt) * 12 + jt) << 9) + lanep * 8;
            *(short8*)dst = ov;
        } else {
            u16* dst = Zbf + h * (N * N) + rc;
            *(short8*)dst = ov;
        }
    }
}

// ---------------- K5: cubic contraction via MFMA bf16, v16 (= v15 + tight reg cap) ----------------
// block = (h, i-tile of 32, d-group of 2). 384 thr = 6 waves; wave w owns k in [w*64,+64).
// launch_bounds(384,4): reg cap 128 (usage ~116) -> 4 waves/SIMD = ~2.67 blocks/CU.
// Tripwire: WRITE_SIZE must stay ~0.4 MB (r7 spill lesson).
__global__ __launch_bounds__(384, 4) void cubic_mfma(
        const u16* __restrict__ Xbf, const u16* __restrict__ Zbf,
        const float* __restrict__ Yt, const float* __restrict__ vjT,
        const float* __restrict__ vkT, float* __restrict__ NumB,
        float* __restrict__ DenB) {
    const int orig = blockIdx.x;             // 0..1631 (1632 = 8 x 204, bijective)
    const int wg = (orig & 7) * 204 + (orig >> 3);
    const int h   = wg / 204;                // one head per XCD
    const int rem = wg - h * 204;
    const int dg  = rem / 12;                // 0..16
    const int it12 = rem - dg * 12;          // 0..11
    const int i0  = it12 * 32;
    const bool dgden = (dg == 16);
    const int d0 = dgden ? 0 : 2 * dg;
    const int d1 = dgden ? 0 : 2 * dg + 1;
    const int tid = threadIdx.x;
    const int w = tid >> 6, lane = tid & 63;
    __shared__ u16 A_lds[2 * 32 * N];        // [t][f(24)][64][8] frag-packed (48 KB)
    __shared__ float red[2][6][32];
    u16* A0 = A_lds;
    u16* A1 = A_lds + 32 * N;
    const u16* Zh = Zbf + h * (N * N);
    const float* Yth = Yt + h * (N * N);
    const float* vjd0 = vjT + h * (D * N) + d0 * N;
    const float* vjd1 = vjT + h * (D * N) + d1 * N;
    const float* vkd0 = vkT + h * (D * N) + d0 * N;
    const float* vkd1 = vkT + h * (D * N) + d1 * N;

    // ---- A-prep: coalesced global reads, frag-packed LDS writes (both tiles)
    // 1536 chunks(short8) per tile; 4 iters x 384 thr
    {
#pragma unroll
        for (int it = 0; it < 4; ++it) {
            const int g = it * 384 + tid;        // 0..1535
            const int row = g / 48;              // 0..31
            const int cb = g - row * 48;
            const int jb = cb * 8;
            const int fi = row >> 4, l15r = row & 15;
            const int js = cb >> 2, sub = cb & 3;
            const int f = fi * 12 + js;          // 0..23
            const int dst = f * 512 + (((l15r | (sub << 4)) ^ (f & 7)) << 3);
            short8 zv = *(const short8*)&Zh[(i0 + row) * N + jb];
            if (dgden) {
                *(short8*)&A0[dst] = zv;
                *(short8*)&A1[dst] = zv;
            } else {
                float4 p0 = *(const float4*)&vjd0[jb];
                float4 p1 = *(const float4*)&vjd0[jb + 4];
                float4 q0 = *(const float4*)&vjd1[jb];
                float4 q1 = *(const float4*)&vjd1[jb + 4];
                float v0[8] = {p0.x, p0.y, p0.z, p0.w, p1.x, p1.y, p1.z, p1.w};
                float v1[8] = {q0.x, q0.y, q0.z, q0.w, q1.x, q1.y, q1.z, q1.w};
                short8 o0, o1;
#pragma unroll
                for (int e = 0; e < 8; ++e) {
                    float zf = bf2f((u16)zv[e]);
                    o0[e] = (short)f2bf(zf * v0[e]);
                    o1[e] = (short)f2bf(zf * v1[e]);
                }
                *(short8*)&A0[dst] = o0;
                *(short8*)&A1[dst] = o1;
            }
        }
    }
    __syncthreads();

    // ---- MFMA main loop: no barriers, k held in accumulators
    f32x4 acc0[2][4], acc1[2][4];
#pragma unroll
    for (int fi = 0; fi < 2; ++fi)
#pragma unroll
        for (int fk = 0; fk < 4; ++fk) {
            acc0[fi][fk] = (f32x4){0.f, 0.f, 0.f, 0.f};
            acc1[fi][fk] = (f32x4){0.f, 0.f, 0.f, 0.f};
        }

    const int l15 = lane & 15;
    // packed-B: wave w covers k-tiles 4w..4w+3; frag (kt, jt) at (kt*12+jt)*512
    const u16* Bp = Xbf + ((h * 24 + w * 4) * 12 << 9) + lane * 8;
    const int KTS = 12 * 512;         // k-tile stride (u16)

#pragma unroll
    for (int js = 0; js < 12; ++js) {
        short8 a0[2], a1[2];
#pragma unroll
        for (int fi = 0; fi < 2; ++fi) {
            const int f = fi * 12 + js;
            const int off = f * 512 + ((lane ^ (f & 7)) << 3);
            a0[fi] = *(const short8*)&A0[off];
            a1[fi] = *(const short8*)&A1[off];
        }
        short8 b[4];
#pragma unroll
        for (int fk = 0; fk < 4; ++fk)
            b[fk] = *(const short8*)&Bp[fk * KTS + js * 512];
        __builtin_amdgcn_s_setprio(1);
#pragma unroll
        for (int fk = 0; fk < 4; ++fk) {
#pragma unroll
            for (int fi = 0; fi < 2; ++fi) {
                acc0[fi][fk] = __builtin_amdgcn_mfma_f32_16x16x32_bf16(a0[fi], b[fk], acc0[fi][fk], 0, 0, 0);
                acc1[fi][fk] = __builtin_amdgcn_mfma_f32_16x16x32_bf16(a1[fi], b[fk], acc1[fi][fk], 0, 0, 0);
            }
        }
        __builtin_amdgcn_s_setprio(0);
    }

    // ---- epilogue: weight by YT[i,k]*vk[k,d], reduce over k; d0 then d1
    const int rbase = (lane >> 4) << 2;
    {   // d0
        float np[2][4];
#pragma unroll
        for (int fi = 0; fi < 2; ++fi)
#pragma unroll
            for (int reg = 0; reg < 4; ++reg) np[fi][reg] = 0.f;
#pragma unroll
        for (int fk = 0; fk < 4; ++fk) {
            const int kcol = w * 64 + fk * 16 + l15;
            const float vkv = dgden ? 1.0f : vkd0[kcol];
#pragma unroll
            for (int fi = 0; fi < 2; ++fi) {
#pragma unroll
                for (int reg = 0; reg < 4; ++reg) {
                    const int irow = i0 + fi * 16 + rbase + reg;
                    const float wgt = Yth[irow * N + kcol] * vkv;
                    np[fi][reg] = fmaf(acc0[fi][fk][reg], wgt, np[fi][reg]);
                }
            }
        }
#pragma unroll
        for (int fi = 0; fi < 2; ++fi) {
#pragma unroll
            for (int reg = 0; reg < 4; ++reg) {
                float v = np[fi][reg];
                v += __shfl_xor(v, 1); v += __shfl_xor(v, 2);
                v += __shfl_xor(v, 4); v += __shfl_xor(v, 8);
                np[fi][reg] = v;
            }
        }
        if (l15 == 0) {
#pragma unroll
            for (int fi = 0; fi < 2; ++fi)
#pragma unroll
                for (int reg = 0; reg < 4; ++reg)
                    red[0][w][fi * 16 + rbase + reg] = np[fi][reg];
        }
    }
    {   // d1
        float np[2][4];
#pragma unroll
        for (int fi = 0; fi < 2; ++fi)
#pragma unroll
            for (int reg = 0; reg < 4; ++reg) np[fi][reg] = 0.f;
#pragma unroll
        for (int fk = 0; fk < 4; ++fk) {
            const int kcol = w * 64 + fk * 16 + l15;
            const float vkv = dgden ? 1.0f : vkd1[kcol];
#pragma unroll
            for (int fi = 0; fi < 2; ++fi) {
#pragma unroll
                for (int reg = 0; reg < 4; ++reg) {
                    const int irow = i0 + fi * 16 + rbase + reg;
                    const float wgt = Yth[irow * N + kcol] * vkv;
                    np[fi][reg] = fmaf(acc1[fi][fk][reg], wgt, np[fi][reg]);
                }
            }
        }
#pragma unroll
        for (int fi = 0; fi < 2; ++fi) {
#pragma unroll
            for (int reg = 0; reg < 4; ++reg) {
                float v = np[fi][reg];
                v += __shfl_xor(v, 1); v += __shfl_xor(v, 2);
                v += __shfl_xor(v, 4); v += __shfl_xor(v, 8);
                np[fi][reg] = v;
            }
        }
        if (l15 == 0) {
#pragma unroll
            for (int fi = 0; fi < 2; ++fi)
#pragma unroll
                for (int reg = 0; reg < 4; ++reg)
                    red[1][w][fi * 16 + rbase + reg] = np[fi][reg];
        }
    }
    __syncthreads();
    if (tid < 32) {
        float s = 0.f;
#pragma unroll
        for (int ww = 0; ww < 6; ++ww) s += red[0][ww][tid];
        if (!dgden) NumB[h * (N * D) + (i0 + tid) * D + 2 * dg] = s;
        else        DenB[h * N + i0 + tid] = s;
    } else if (tid < 64 && !dgden) {
        const int i = tid - 32;
        float s = 0.f;
#pragma unroll
        for (int ww = 0; ww < 6; ++ww) s += red[1][ww][i];
        NumB[h * (N * D) + (i0 + i) * D + 2 * dg + 1] = s;
    }
}

// ---------------- K6: normalize + fp32 output [n, h*D+d] ----------------
__global__ void out_kernel(const float* __restrict__ NumB, const float* __restrict__ DenB,
                           float* __restrict__ out) {
    int idx = blockIdx.x * 256 + threadIdx.x;  // 0..98303
    int n = idx >> 8;
    int ch = idx & 255;
    int hh = ch >> 5, d = ch & 31;
    float v = NumB[hh * (N * D) + n * D + d] / (DenB[hh * N + n] + EPS);
    out[idx] = v;
}

extern "C" void kernel_launch(void* const* d_in, const int* in_sizes, int n_in,
                              void* d_out, int out_size, void* d_ws, size_t ws_size,
                              hipStream_t stream) {
    const float* hs = (const float*)d_in[0];
    const float* W  = (const float*)d_in[1];
    float* ws = (float*)d_ws;
    float* proj  = ws + PROJ_OFF;
    float* S     = ws + S_OFF;
    float* projT = ws + VJT_OFF;    // vj rows, then vk rows at +H*D*N
    float* mX    = ws + MX_OFF;
    float* NumB  = ws + NUM_OFF;
    float* DenB  = ws + DEN_OFF;
    u16*   Xbf   = (u16*)(ws + XBF_OFF);
    u16*   Zbf   = (u16*)(ws + ZBF_OFF);
    u32*   keys  = (u32*)(ws + KEYS_OFF);   // 3*H*N keys
    u16*   Lbf   = (u16*)(ws + LBF_OFF);    // bf16 a,b,c
    float* out = (float*)d_out;

    hipMemsetAsync(keys, 0, 3 * H * N * sizeof(u32), stream);
    proj_kernel<<<dim3(20, 6), 256, 0, stream>>>(hs, W, proj, projT, Lbf);
    scores_mfma<<<dim3(9, 8, 3), 256, 0, stream>>>(Lbf, S, keys);
    reduce_mx_kernel<<<8, 64, 0, stream>>>(keys, mX);
    exp_kernel<<<1728, 256, 0, stream>>>(S, mX, keys, Xbf, Zbf);
    cubic_mfma<<<dim3(1632), 384, 0, stream>>>(Xbf, Zbf, S + HNN, ws + VJT_OFF,
                                               ws + VKT_OFF, NumB, DenB);
    out_kernel<<<(H * N * D) / 256, 256, 0, stream>>>(NumB, DenB, out);
}